// Round 3
// baseline (2002.170 us; speedup 1.0000x reference)
//
#include <hip/hip_runtime.h>

#define B_   1024
#define TE   168
#define TD   24
#define F_   64
#define H_   128
#define H2_  256
#define G_   512

// ---- workspace float offsets ----
#define OFF_WhT    0          // dec Wh row-major fp16 [128][256] (32768 halfs)
#define OFF_dWihT  16384      // dec dWih row-major fp16 [512][128] (65536 halfs)
#define OFF_dWhhT  49152      // dec dWhh row-major fp16 [512][128] (65536 halfs)
#define OFF_ENCB   81920
#define OFF_MIDB   82432
#define OFF_DECB   82944
#define OFF_W16    83456      // fp16 row-major weight block (half offsets below)
#define W16_We     0          // [128][256]
#define W16_Wi     32768      // [128][64]
#define W16_Vd     40960      // [64][128]
#define W16_eWih   49152      // [512][64]
#define W16_eWhh   81920      // [512][128]
#define W16_mWih   147456     // [512][128]
#define W16_mWhh   212992     // [512][128]
#define W16_Wx     278528     // [128][128]
#define W16_TOT    294912     // halfs
#define OFF_MID    230912                         // half [1024][168][128]: h_enc, overwritten in-place by midH
#define OFF_WX     (OFF_MID + (B_*TE*H_)/2)       // half [1024][168][128]
#define OFF_STH    (OFF_WX  + (B_*TE*H_)/2)
#define OFF_STC    (OFF_STH + B_*H_)
#define WS_FLOATS  (OFF_STC + B_*H_)

typedef _Float16 h2 __attribute__((ext_vector_type(2)));
typedef _Float16 f16x8 __attribute__((ext_vector_type(8)));
typedef float    f32x4 __attribute__((ext_vector_type(4)));

__device__ __forceinline__ float fexp2(float x) { return __builtin_amdgcn_exp2f(x); }
__device__ __forceinline__ float frcp(float x)  { return __builtin_amdgcn_rcpf(x); }
#define LOG2E 1.4426950408889634f

__device__ __forceinline__ float sigm(float x) {
    return frcp(1.f + fexp2(-LOG2E * x));
}
__device__ __forceinline__ float tanh_fast(float x) {
    float e = fexp2(2.f * LOG2E * x);
    return 1.f - 2.f * frcp(e + 1.f);
}

__device__ __forceinline__ float fdot2(h2 a, h2 b, float c) {
#if __has_builtin(__builtin_amdgcn_fdot2)
    return __builtin_amdgcn_fdot2(a, b, c, false);
#else
    return c + (float)a[0] * (float)b[0] + (float)a[1] * (float)b[1];
#endif
}

#define SH(V,I)  __builtin_shufflevector(V, V, 2*(I), 2*(I)+1)
// 8-element fp16 dot: HV, WV are f16x8
#define DOT8(ACC, HV, WV) { \
    ACC = fdot2(SH(HV,0), SH(WV,0), ACC); \
    ACC = fdot2(SH(HV,1), SH(WV,1), ACC); \
    ACC = fdot2(SH(HV,2), SH(WV,2), ACC); \
    ACC = fdot2(SH(HV,3), SH(WV,3), ACC); \
}

__device__ __forceinline__ f32x4 mfma16(f16x8 a, f16x8 b, f32x4 c) {
    return __builtin_amdgcn_mfma_f32_16x16x32_f16(a, b, c, 0, 0, 0);
}

// ---------------- prep: row-major fp16 weight conversions + summed biases ----------------
struct PrepArgs {
    const float *We, *Wi, *Vd, *eWih, *eWhh, *eBih, *eBhh,
                *mWih, *mWhh, *mBih, *mBhh, *Wx, *Wh, *dWih, *dWhh, *dBih, *dBhh;
};

__global__ void prep_kernel(PrepArgs a, float* __restrict__ ws) {
    int sec  = blockIdx.x >> 2;
    int base = (blockIdx.x & 3) * blockDim.x + threadIdx.x;
    const int stride = blockDim.x * 4;
    _Float16* w16 = (_Float16*)(ws + OFF_W16);

    if (sec <= 2) {
        // dec weights: straight row-major fp16 conversion
        const float* src = (sec == 0) ? a.Wh : (sec == 1) ? a.dWih : a.dWhh;
        int n = (sec == 0) ? 32768 : 65536;
        int off = (sec == 0) ? OFF_WhT : (sec == 1) ? OFF_dWihT : OFF_dWhhT;
        _Float16* hd = (_Float16*)(ws + off);
        for (int o = base; o < n; o += stride) hd[o] = (_Float16)src[o];
    } else if (sec == 3) {
        for (int i = base; i < 512; i += stride) ws[OFF_ENCB + i] = a.eBih[i] + a.eBhh[i];
    } else if (sec == 4) {
        for (int i = base; i < 512; i += stride) ws[OFF_MIDB + i] = a.mBih[i] + a.mBhh[i];
    } else if (sec == 5) {
        for (int i = base; i < 512; i += stride) ws[OFF_DECB + i] = a.dBih[i] + a.dBhh[i];
    } else if (sec <= 13) {
        const int dsto[8] = {W16_We, W16_Wi, W16_Vd, W16_eWih, W16_eWhh, W16_mWih, W16_mWhh, W16_Wx};
        const int cnt[8]  = {32768, 8192, 8192, 32768, 65536, 65536, 65536, 16384};
        const float* srcs[8] = {a.We, a.Wi, a.Vd, a.eWih, a.eWhh, a.mWih, a.mWhh, a.Wx};
        int k = sec - 6;
        const float* s = srcs[k];
        _Float16* d = w16 + dsto[k];
        int n = cnt[k];
        for (int i = base; i < n; i += stride) d[i] = (_Float16)s[i];
    }
}

// ---------------- encoder: 64 blocks x 512 thr, 16 rows/block, weights register-resident ----------------
__global__ __launch_bounds__(512, 1) void enc_kernel(
    const float* __restrict__ x_all,
    const float* __restrict__ Wi_b,
    const float* __restrict__ Vd_b,
    float* __restrict__ ws)
{
    __shared__ __align__(16) _Float16 m1In[16][328];   // [h(0:128)|c(128:256)|x(256:320)]
    __shared__ __align__(16) _Float16 encIn[16][200];  // [xin(0:64)|h_enc(64:192)]
    __shared__ __align__(16) _Float16 avT[16][136];    // tanh(m1) (K=128)
    __shared__ __align__(16) float sS[16][68];         // raw attention scores
    __shared__ __align__(16) float xf[16][64];         // current x fp32
    __shared__ __align__(16) float cE[16][132];        // enc c fp32 master
    __shared__ float bWi[H_], bVd[F_], bE[G_];

    const int tid  = threadIdx.x;
    const int wave = tid >> 6;
    const int lane = tid & 63;
    const int g    = lane >> 4;   // k-group (A/B frag) / row-quad (C frag)
    const int cc   = lane & 15;   // A row / B col / C col
    const int b0   = blockIdx.x * 16;
    const int col  = wave * 16 + cc;

    for (int i = tid; i < 16 * 328; i += 512) ((_Float16*)m1In)[i]  = (_Float16)0.f;
    for (int i = tid; i < 16 * 200; i += 512) ((_Float16*)encIn)[i] = (_Float16)0.f;
    for (int i = tid; i < 16 * 132; i += 512) ((float*)cE)[i] = 0.f;
    if (tid < H_) bWi[tid] = Wi_b[tid];
    if (tid < F_) bVd[tid] = Vd_b[tid];
    bE[tid] = ws[OFF_ENCB + tid];
    if (tid < 256) {  // x for t=0
        int m = tid >> 4, c4 = (tid & 15) * 4;
        float4 v = *(const float4*)&x_all[((size_t)(b0 + m) * TE + 0) * F_ + c4];
        *(float4*)&xf[m][c4] = v;
        m1In[m][256 + c4]     = (_Float16)v.x;
        m1In[m][256 + c4 + 1] = (_Float16)v.y;
        m1In[m][256 + c4 + 2] = (_Float16)v.z;
        m1In[m][256 + c4 + 3] = (_Float16)v.w;
    }

    // ---- persistent per-wave B-fragments (fixed across all t) ----
    const _Float16* w16 = (const _Float16*)(ws + OFF_W16);
    f16x8 wWe[8], wWi[2], wVd[4], wIh[4][2], wHh[4][4];
    {
        const _Float16* p = w16 + W16_We + (size_t)col * 256 + 8 * g;
        #pragma unroll
        for (int ks = 0; ks < 8; ++ks) wWe[ks] = *(const f16x8*)(p + ks * 32);
        const _Float16* p2 = w16 + W16_Wi + (size_t)col * 64 + 8 * g;
        wWi[0] = *(const f16x8*)(p2);
        wWi[1] = *(const f16x8*)(p2 + 32);
        if (wave < 4) {
            const _Float16* p3 = w16 + W16_Vd + (size_t)col * 128 + 8 * g;
            #pragma unroll
            for (int ks = 0; ks < 4; ++ks) wVd[ks] = *(const f16x8*)(p3 + ks * 32);
        } else {
            #pragma unroll
            for (int ks = 0; ks < 4; ++ks) wVd[ks] = f16x8{};
        }
        #pragma unroll
        for (int q = 0; q < 4; ++q) {
            const _Float16* pi = w16 + W16_eWih + (size_t)(q * 128 + col) * 64 + 8 * g;
            wIh[q][0] = *(const f16x8*)(pi);
            wIh[q][1] = *(const f16x8*)(pi + 32);
            const _Float16* ph = w16 + W16_eWhh + (size_t)(q * 128 + col) * 128 + 8 * g;
            #pragma unroll
            for (int ks = 0; ks < 4; ++ks) wHh[q][ks] = *(const f16x8*)(ph + ks * 32);
        }
    }
    _Float16* hencG = (_Float16*)(ws + OFF_MID);
    __syncthreads();

    float4 xr = make_float4(0.f, 0.f, 0.f, 0.f);  // x_{t+1} prefetch (waves 4-7)

    for (int t = 0; t < TE; ++t) {
        // ---- P1: m1 = [h|c|x] @ [We|Wi]^T  -> av = tanh(m1 + bWi)
        {
            f16x8 aF[10];
            #pragma unroll
            for (int ks = 0; ks < 10; ++ks)
                aF[ks] = *(const f16x8*)&m1In[cc][ks * 32 + 8 * g];
            f32x4 acc = {0.f, 0.f, 0.f, 0.f};
            #pragma unroll
            for (int ks = 0; ks < 8; ++ks)
                acc = mfma16(aF[ks], wWe[ks], acc);
            acc = mfma16(aF[8], wWi[0], acc);
            acc = mfma16(aF[9], wWi[1], acc);
            float bw = bWi[col];
            #pragma unroll
            for (int r = 0; r < 4; ++r)
                avT[4 * g + r][col] = (_Float16)tanh_fast(acc[r] + bw);
        }
        __syncthreads();

        // ---- P2: s = av @ Vd^T (waves 0-3, K=128); waves 4-7 prefetch x_{t+1}
        if (wave < 4) {
            f16x8 aF[4];
            #pragma unroll
            for (int ks = 0; ks < 4; ++ks)
                aF[ks] = *(const f16x8*)&avT[cc][ks * 32 + 8 * g];
            f32x4 acc = {0.f, 0.f, 0.f, 0.f};
            #pragma unroll
            for (int ks = 0; ks < 4; ++ks)
                acc = mfma16(aF[ks], wVd[ks], acc);
            float bv = bVd[col];
            #pragma unroll
            for (int r = 0; r < 4; ++r)
                sS[4 * g + r][col] = acc[r] + bv;
        } else if (t + 1 < TE) {
            int q = tid - 256, m = q >> 4, c4 = (q & 15) * 4;
            xr = *(const float4*)&x_all[((size_t)(b0 + m) * TE + (t + 1)) * F_ + c4];
        }
        __syncthreads();

        // ---- P2b: softmax over 64 + xin = x * softmax(s). row = half-wave
        {
            int m = tid >> 5, c = tid & 31;
            float v0 = sS[m][c], v1 = sS[m][c + 32];
            float mx = fmaxf(v0, v1);
            #pragma unroll
            for (int off = 16; off > 0; off >>= 1) mx = fmaxf(mx, __shfl_xor(mx, off, 64));
            float e0 = fexp2((v0 - mx) * LOG2E);
            float e1 = fexp2((v1 - mx) * LOG2E);
            float sm = e0 + e1;
            #pragma unroll
            for (int off = 16; off > 0; off >>= 1) sm += __shfl_xor(sm, off, 64);
            float rs = frcp(sm);
            encIn[m][c]      = (_Float16)(xf[m][c]      * e0 * rs);
            encIn[m][c + 32] = (_Float16)(xf[m][c + 32] * e1 * rs);
        }
        __syncthreads();

        // ---- P4: enc gates = [xin|h] @ [eWih|eWhh]^T  (K=192; 4 gate-tiles per wave)
        f32x4 ge[4];
        {
            f16x8 aF[6];
            #pragma unroll
            for (int ks = 0; ks < 6; ++ks)
                aF[ks] = *(const f16x8*)&encIn[cc][ks * 32 + 8 * g];
            #pragma unroll
            for (int q = 0; q < 4; ++q) {
                f32x4 acc = {0.f, 0.f, 0.f, 0.f};
                acc = mfma16(aF[0], wIh[q][0], acc);
                acc = mfma16(aF[1], wIh[q][1], acc);
                #pragma unroll
                for (int ks = 0; ks < 4; ++ks)
                    acc = mfma16(aF[2 + ks], wHh[q][ks], acc);
                ge[q] = acc;
            }
        }
        __syncthreads();   // all encIn reads done
        // ---- ep: enc LSTM cell (in-register gates) + h_enc global store + x install
        {
            float bi = bE[col], bf = bE[col + 128], bg = bE[col + 256], bo = bE[col + 384];
            #pragma unroll
            for (int r = 0; r < 4; ++r) {
                int m = 4 * g + r;
                float gi = ge[0][r] + bi, gf = ge[1][r] + bf,
                      gg = ge[2][r] + bg, go = ge[3][r] + bo;
                float cn = sigm(gf) * cE[m][col] + sigm(gi) * tanh_fast(gg);
                float h  = sigm(go) * tanh_fast(cn);
                cE[m][col] = cn;
                _Float16 hh = (_Float16)h;
                encIn[m][64 + col] = hh;
                m1In[m][col]       = hh;
                m1In[m][128 + col] = (_Float16)cn;
                hencG[((size_t)(b0 + m) * TE + t) * H_ + col] = hh;
            }
            if (tid >= 256 && t + 1 < TE) {
                int q = tid - 256, m = q >> 4, c4 = (q & 15) * 4;
                *(float4*)&xf[m][c4] = xr;
                m1In[m][256 + c4]     = (_Float16)xr.x;
                m1In[m][256 + c4 + 1] = (_Float16)xr.y;
                m1In[m][256 + c4 + 2] = (_Float16)xr.z;
                m1In[m][256 + c4 + 3] = (_Float16)xr.w;
            }
        }
        __syncthreads();
    }
}

// ---------------- mid LSTM: 64 blocks x 512 thr, 16 rows/block, weights register-resident ----------------
__global__ __launch_bounds__(512, 1) void mid_kernel(
    const float* __restrict__ Wx_b,
    float* __restrict__ ws)
{
    __shared__ __align__(16) _Float16 midIn[16][264];  // [h_enc(0:128)|h_mid(128:256)]
    __shared__ __align__(16) float cM[16][132];        // mid c fp32 master
    __shared__ float bM[G_], bWx[H_];

    const int tid  = threadIdx.x;
    const int wave = tid >> 6;
    const int lane = tid & 63;
    const int g    = lane >> 4;
    const int cc   = lane & 15;
    const int b0   = blockIdx.x * 16;
    const int col  = wave * 16 + cc;

    for (int i = tid; i < 16 * 264; i += 512) ((_Float16*)midIn)[i] = (_Float16)0.f;
    for (int i = tid; i < 16 * 132; i += 512) ((float*)cM)[i] = 0.f;
    if (tid < H_) bWx[tid] = Wx_b[tid];
    bM[tid] = ws[OFF_MIDB + tid];

    // ---- persistent per-wave B-fragments ----
    const _Float16* w16 = (const _Float16*)(ws + OFF_W16);
    f16x8 wIhB[4][4], wHhB[4][4], wWx[4];
    {
        #pragma unroll
        for (int q = 0; q < 4; ++q) {
            const _Float16* pi = w16 + W16_mWih + (size_t)(q * 128 + col) * 128 + 8 * g;
            const _Float16* ph = w16 + W16_mWhh + (size_t)(q * 128 + col) * 128 + 8 * g;
            #pragma unroll
            for (int ks = 0; ks < 4; ++ks) {
                wIhB[q][ks] = *(const f16x8*)(pi + ks * 32);
                wHhB[q][ks] = *(const f16x8*)(ph + ks * 32);
            }
        }
        const _Float16* px = w16 + W16_Wx + (size_t)col * 128 + 8 * g;
        #pragma unroll
        for (int ks = 0; ks < 4; ++ks) wWx[ks] = *(const f16x8*)(px + ks * 32);
    }

    _Float16* hencG = (_Float16*)(ws + OFF_MID);   // h_enc in, midH out (in-place)
    _Float16* wxH   = (_Float16*)(ws + OFF_WX);
    __syncthreads();

    // install h_enc(0)
    if (tid < 256) {
        int m = tid >> 4, s8 = (tid & 15) * 8;
        *(f16x8*)&midIn[m][s8] = *(const f16x8*)&hencG[((size_t)(b0 + m) * TE + 0) * H_ + s8];
    }
    __syncthreads();

    f16x8 hpre = {};
    f32x4 accx = {0.f, 0.f, 0.f, 0.f};

    for (int t = 0; t < TE; ++t) {
        // ---- P6: mid gates = [h_enc(t)|h_mid(t-1)] @ [mWih|mWhh]^T (K=256) + wx(t-1)
        f32x4 gm[4];
        {
            f16x8 aF[8];
            #pragma unroll
            for (int ks = 0; ks < 8; ++ks)
                aF[ks] = *(const f16x8*)&midIn[cc][ks * 32 + 8 * g];
            #pragma unroll
            for (int q = 0; q < 4; ++q) {
                f32x4 acc = {0.f, 0.f, 0.f, 0.f};
                #pragma unroll
                for (int ks = 0; ks < 4; ++ks)
                    acc = mfma16(aF[ks], wIhB[q][ks], acc);
                #pragma unroll
                for (int ks = 0; ks < 4; ++ks)
                    acc = mfma16(aF[4 + ks], wHhB[q][ks], acc);
                gm[q] = acc;
            }
            if (t > 0) {   // wx(t-1) = h_mid(t-1) @ Wx^T (aF[4..7] already hold h_mid(t-1))
                f32x4 acc = {0.f, 0.f, 0.f, 0.f};
                #pragma unroll
                for (int ks = 0; ks < 4; ++ks)
                    acc = mfma16(aF[4 + ks], wWx[ks], acc);
                accx = acc;
            }
        }
        if (tid < 256 && t + 1 < TE) {   // prefetch h_enc(t+1)
            int m = tid >> 4, s8 = (tid & 15) * 8;
            hpre = *(const f16x8*)&hencG[((size_t)(b0 + m) * TE + (t + 1)) * H_ + s8];
        }
        __syncthreads();

        // ---- ep: mid LSTM cell + midH store (in-place over h_enc) + wx(t-1) store + h_enc(t+1) install
        {
            float bi = bM[col], bf = bM[col + 128], bg = bM[col + 256], bo = bM[col + 384];
            float bw = bWx[col];
            #pragma unroll
            for (int r = 0; r < 4; ++r) {
                int m = 4 * g + r;
                float gi = gm[0][r] + bi, gf = gm[1][r] + bf,
                      gg = gm[2][r] + bg, go = gm[3][r] + bo;
                float cn = sigm(gf) * cM[m][col] + sigm(gi) * tanh_fast(gg);
                float h  = sigm(go) * tanh_fast(cn);
                cM[m][col] = cn;
                _Float16 hh = (_Float16)h;
                midIn[m][128 + col] = hh;
                hencG[((size_t)(b0 + m) * TE + t) * H_ + col] = hh;   // midH(t)
                if (t > 0)
                    wxH[((size_t)(b0 + m) * TE + (t - 1)) * H_ + col] = (_Float16)(accx[r] + bw);
            }
            if (tid < 256 && t + 1 < TE) {
                int m = tid >> 4, s8 = (tid & 15) * 8;
                *(f16x8*)&midIn[m][s8] = hpre;
            }
        }
        __syncthreads();
    }

    // final wx(TE-1)
    {
        f16x8 ax[4];
        #pragma unroll
        for (int ks = 0; ks < 4; ++ks)
            ax[ks] = *(const f16x8*)&midIn[cc][128 + ks * 32 + 8 * g];
        f32x4 acc = {0.f, 0.f, 0.f, 0.f};
        #pragma unroll
        for (int ks = 0; ks < 4; ++ks)
            acc = mfma16(ax[ks], wWx[ks], acc);
        float bw = bWx[col];
        #pragma unroll
        for (int r = 0; r < 4; ++r) {
            int m = 4 * g + r;
            wxH[((size_t)(b0 + m) * TE + (TE - 1)) * H_ + col] = (_Float16)(acc[r] + bw);
        }
    }
    // final states for decoder
    for (int idx = tid; idx < 2048; idx += 512) {
        int m = idx >> 7, j = idx & 127;
        ws[OFF_STH + (b0 + m) * H_ + j] = (float)midIn[m][128 + j];
        ws[OFF_STC + (b0 + m) * H_ + j] = cM[m][j];
    }
}

// ---------------- decoder: 1024 blocks x 512 thr, 1 row/block, LDS-staged wx/mid, reg weights ----------------
__global__ __launch_bounds__(512, 1) void dec_kernel(
    const float* __restrict__ Vw_in,
    const float* __restrict__ Vb_in,
    const float* __restrict__ rw_in,
    const float* __restrict__ rb_in,
    const float* __restrict__ ws,
    float* __restrict__ out)
{
    __shared__ __align__(16) _Float16 wxL[TE][136];    // padded +8 halfs (bank spread)
    __shared__ __align__(16) _Float16 midL[TE][136];
    __shared__ __align__(16) _Float16 hcH[H2_];        // [h fp16 (0:128) | c fp16 (128:256)]
    __shared__ __align__(16) _Float16 dinH[H_];        // dec_in fp16
    __shared__ __align__(16) float hF[H_];             // h fp32 (output dot)
    __shared__ __align__(16) float cD[H_];             // c fp32 master
    __shared__ __align__(16) float qv[H_];             // q result fp32
    __shared__ __align__(16) float sv[TE];             // scores
    __shared__ __align__(16) float dpart[4][H_];       // P3 partials
    __shared__ __align__(16) float ggs[G_];            // gate accums
    __shared__ float bDL[G_], VwL[H_], rwL[H_];

    const int tid = threadIdx.x;
    const int b   = blockIdx.x;
    const float Vb = Vb_in[0], rb = rb_in[0];

    // ---- per-thread register-resident weights ----
    const _Float16* Wh16  = (const _Float16*)(ws + OFF_WhT);    // [128][256]
    const _Float16* dIh16 = (const _Float16*)(ws + OFF_dWihT);  // [512][128]
    const _Float16* dHh16 = (const _Float16*)(ws + OFF_dWhhT);  // [512][128]
    const int j1  = tid >> 2;        // P1 output col (0..127)
    const int ks1 = tid & 3;         // P1 K-slice (64 each)

    f16x8 wWh[8], wIh[16], wHh[16];
    {
        const _Float16* p = Wh16 + (size_t)j1 * 256 + ks1 * 64;
        #pragma unroll
        for (int k = 0; k < 8; ++k) wWh[k] = *(const f16x8*)(p + k * 8);
        const _Float16* pi = dIh16 + (size_t)tid * 128;
        const _Float16* ph = dHh16 + (size_t)tid * 128;
        #pragma unroll
        for (int k = 0; k < 16; ++k) {
            wIh[k] = *(const f16x8*)(pi + k * 8);
            wHh[k] = *(const f16x8*)(ph + k * 8);
        }
    }

    // ---- stage this row's wx + mid into LDS (once) ----
    {
        const _Float16* wxG  = (const _Float16*)(ws + OFF_WX)  + (size_t)b * TE * H_;
        const _Float16* midG = (const _Float16*)(ws + OFF_MID) + (size_t)b * TE * H_;
        for (int i = tid; i < TE * 16; i += 512) {
            int tp = i >> 4, c8 = (i & 15) * 8;
            *(f16x8*)&wxL[tp][c8]  = *(const f16x8*)(wxG  + (size_t)tp * H_ + c8);
            *(f16x8*)&midL[tp][c8] = *(const f16x8*)(midG + (size_t)tp * H_ + c8);
        }
    }
    // ---- init state + small vectors ----
    if (tid < 128) {
        float sh = ws[OFF_STH + (size_t)b * H_ + tid];
        float sc = ws[OFF_STC + (size_t)b * H_ + tid];
        hcH[tid]       = (_Float16)sh;
        hcH[128 + tid] = (_Float16)sc;
        cD[tid] = sc;
        VwL[tid] = Vw_in[tid];
        rwL[tid] = rw_in[tid];
    }
    bDL[tid] = ws[OFF_DECB + tid];
    __syncthreads();

    for (int td = 0; td < TD; ++td) {
        // ---- P1: q = [h|c] @ Wh^T.  thread = (j1, ks1): K=64 slice, 4-thread reduce
        {
            const _Float16* hp = hcH + ks1 * 64;
            float acc = 0.f;
            #pragma unroll
            for (int k8 = 0; k8 < 8; ++k8) {
                f16x8 hv = *(const f16x8*)(hp + k8 * 8);
                DOT8(acc, hv, wWh[k8]);
            }
            acc += __shfl_xor(acc, 1, 64);
            acc += __shfl_xor(acc, 2, 64);
            if (ks1 == 0) qv[j1] = acc;
        }
        __syncthreads();

        // ---- P2: scores. thread = (tp, half): 64 tanh-dot each, pair reduce
        if (tid < 2 * TE) {
            int tp = tid >> 1, hf = tid & 1;
            const _Float16* wxp = &wxL[tp][hf * 64];
            const float* qp = qv + hf * 64;
            const float* vp = VwL + hf * 64;
            float acc = 0.f;
            #pragma unroll 4
            for (int k8 = 0; k8 < 8; ++k8) {
                f16x8 wv = *(const f16x8*)(wxp + k8 * 8);
                float4 q0 = *(const float4*)(qp + k8 * 8);
                float4 q1 = *(const float4*)(qp + k8 * 8 + 4);
                float4 v0 = *(const float4*)(vp + k8 * 8);
                float4 v1 = *(const float4*)(vp + k8 * 8 + 4);
                acc += tanh_fast(q0.x + (float)wv[0]) * v0.x + tanh_fast(q0.y + (float)wv[1]) * v0.y
                     + tanh_fast(q0.z + (float)wv[2]) * v0.z + tanh_fast(q0.w + (float)wv[3]) * v0.w;
                acc += tanh_fast(q1.x + (float)wv[4]) * v1.x + tanh_fast(q1.y + (float)wv[5]) * v1.y
                     + tanh_fast(q1.z + (float)wv[6]) * v1.z + tanh_fast(q1.w + (float)wv[7]) * v1.w;
            }
            acc += __shfl_xor(acc, 1, 64);
            if (hf == 0) sv[tp] = acc + Vb;
        }
        __syncthreads();

        // ---- P3: dec_in partials. thread = (j, slice of 42 tp)
        {
            int j = tid & 127, sl = tid >> 7;
            int t0 = sl * 42;
            float acc = 0.f;
            for (int tp = t0; tp < t0 + 42; ++tp)
                acc = __builtin_fmaf(sv[tp], (float)midL[tp][j], acc);
            dpart[sl][j] = acc;
        }
        __syncthreads();
        // ---- P3b: combine -> dinH fp16
        if (tid < 128) {
            float d = (dpart[0][tid] + dpart[1][tid]) + (dpart[2][tid] + dpart[3][tid]);
            dinH[tid] = (_Float16)d;
        }
        __syncthreads();

        // ---- P4: gates. thread = gate g: K=128(din) + K=128(h), all-broadcast LDS reads
        {
            float acc = bDL[tid];
            #pragma unroll 8
            for (int k8 = 0; k8 < 16; ++k8) {
                f16x8 dv = *(const f16x8*)(dinH + k8 * 8);
                DOT8(acc, dv, wIh[k8]);
            }
            #pragma unroll 8
            for (int k8 = 0; k8 < 16; ++k8) {
                f16x8 hv = *(const f16x8*)(hcH + k8 * 8);
                DOT8(acc, hv, wHh[k8]);
            }
            ggs[tid] = acc;
        }
        __syncthreads();

        // ---- P5: LSTM cell
        if (tid < 128) {
            float gi = ggs[tid], gf = ggs[tid + 128], gg = ggs[tid + 256], go = ggs[tid + 384];
            float cn = sigm(gf) * cD[tid] + sigm(gi) * tanh_fast(gg);
            float h  = sigm(go) * tanh_fast(cn);
            cD[tid] = cn;
            hF[tid] = h;
            hcH[tid]       = (_Float16)h;
            hcH[128 + tid] = (_Float16)cn;
        }
        __syncthreads();

        // ---- P6: output dot (overlaps next P1; no trailing barrier)
        if (tid < 64) {
            float v = hF[tid] * rwL[tid] + hF[tid + 64] * rwL[tid + 64];
            #pragma unroll
            for (int off = 32; off > 0; off >>= 1) v += __shfl_xor(v, off, 64);
            if (tid == 0) out[(size_t)b * TD + td] = v + rb;
        }
    }
}

extern "C" void kernel_launch(void* const* d_in, const int* in_sizes, int n_in,
                              void* d_out, int out_size, void* d_ws, size_t ws_size,
                              hipStream_t stream)
{
    (void)in_sizes; (void)n_in; (void)out_size;
    if (ws_size < (size_t)WS_FLOATS * sizeof(float)) return;

    const float* x_all = (const float*)d_in[0];
    const float* Wi_b  = (const float*)d_in[3];
    const float* Vd_b  = (const float*)d_in[6];
    const float* Wx_b  = (const float*)d_in[16];
    const float* V_w   = (const float*)d_in[18];
    const float* V_b   = (const float*)d_in[19];
    const float* reg_w = (const float*)d_in[24];
    const float* reg_b = (const float*)d_in[25];
    float* ws  = (float*)d_ws;
    float* out = (float*)d_out;

    PrepArgs pa{
        (const float*)d_in[4],  // We_w
        (const float*)d_in[2],  // Wi_w
        (const float*)d_in[5],  // Vd_w
        (const float*)d_in[7],  // enc_Wih
        (const float*)d_in[8],  // enc_Whh
        (const float*)d_in[9],  // enc_bih
        (const float*)d_in[10], // enc_bhh
        (const float*)d_in[11], // mid_Wih
        (const float*)d_in[12], // mid_Whh
        (const float*)d_in[13], // mid_bih
        (const float*)d_in[14], // mid_bhh
        (const float*)d_in[15], // Wx_w
        (const float*)d_in[17], // Wh_w
        (const float*)d_in[20], // dec_Wih
        (const float*)d_in[21], // dec_Whh
        (const float*)d_in[22], // dec_bih
        (const float*)d_in[23]  // dec_bhh
    };

    prep_kernel<<<56, 256, 0, stream>>>(pa, ws);
    enc_kernel<<<64, 512, 0, stream>>>(x_all, Wi_b, Vd_b, ws);
    mid_kernel<<<64, 512, 0, stream>>>(Wx_b, ws);
    dec_kernel<<<1024, 512, 0, stream>>>(V_w, V_b, reg_w, reg_b, ws, out);
}